// Round 15
// baseline (2621.630 us; speedup 1.0000x reference)
//
#include <hip/hip_runtime.h>
#include <math.h>

#define T_STEPS 256
#define NB 4096

// ---- fast fp64 helpers (pure VALU, no LDS) ----
__device__ __forceinline__ double frcp(double d){
    double r;
    asm("v_rcp_f64 %0, %1" : "=v"(r) : "v"(d));
    r = r * fma(-d, r, 2.0);          // NR 1
    r = r * fma(-d, r, 2.0);          // NR 2 -> ~0.5 ulp
    return r;
}
__device__ __forceinline__ double fexp(double y){   // e^y, |y| < ~700, rel err ~1e-13
    const double MAGIC   = 6755399441055744.0;      // 2^52 + 2^51
    const double INV_LN2 = 1.4426950408889634074;
    const double LN2_HI  = 6.93147180369123816490e-01;
    const double LN2_LO  = 1.90821492927058770002e-10;
    double zz = fma(y, INV_LN2, MAGIC);
    int    ni = __double2loint(zz);
    double nd = zz - MAGIC;                         // n (exact)
    double r  = fma(nd, -LN2_HI, y);
    r = fma(nd, -LN2_LO, r);                        // r in [-0.347, 0.347]
    double p = 2.7557319223985890653e-7;            // 1/10!
    p = fma(p, r, 2.7557319223985888276e-6);        // 1/9!
    p = fma(p, r, 2.4801587301587301566e-5);
    p = fma(p, r, 1.9841269841269841253e-4);
    p = fma(p, r, 1.3888888888888889419e-3);
    p = fma(p, r, 8.3333333333333332177e-3);
    p = fma(p, r, 4.1666666666666664354e-2);
    p = fma(p, r, 1.6666666666666665741e-1);
    p = fma(p, r, 5.0e-1);
    p = fma(p, r, 1.0);
    p = fma(p, r, 1.0);                             // e^r
    double sc = __longlong_as_double(((long long)(1023 + ni)) << 52);  // 2^n
    return p * sc;
}

__global__ __launch_bounds__(256, 2)
void rssm_kernel(const float* __restrict__ X, const float* __restrict__ A,
                 const float* __restrict__ H0, const float* __restrict__ G,
                 const float* __restrict__ Wih, const float* __restrict__ bih,
                 const float* __restrict__ Whh, const float* __restrict__ bhh,
                 const float* __restrict__ Wenc, const float* __restrict__ benc,
                 const float* __restrict__ Wdec, const float* __restrict__ bdec,
                 float* __restrict__ out)   // d_out is FP32
{
    // Static LDS, 63,488 B total (2 blocks/CU). All weights + biases in LDS.
    __shared__ float  sWihz[96][65];                    // z-part gather (bank r+c, conflict-free)
    __shared__ float  sWiha[96][18];                    // a-part, float2 reads (2-way-free banks)
    __shared__ __align__(16) float sWhhQ[3][8][132];    // W_hh packed: [gate][kquad][4*i+d], b128 reads
    __shared__ __align__(16) float sEncP [16][132];     // enc h-part packed: [k2][4*jp+d]
    __shared__ __align__(16) float sEncEP[5][132];      // enc e-part packed
    __shared__ __align__(16) float sWdech[10][36];      // dec h-part rows, float4 reads
    __shared__ float  sWdecz[10][65];                   // dec z-part gather
    __shared__ __align__(16) double sHd[8][34];         // per-element fp64 h (broadcast b128 reads)
    __shared__ __align__(16) double sBiasD[32][5];      // {br, bz, bnh, bni} per component (padded)
    __shared__ float  sBencF[64];                       // enc biases

    const int tid = threadIdx.x;
    const int i   = tid & 31;          // component lane within element
    const int e   = tid >> 5;          // element slot in block (0..7)
    const int n   = blockIdx.x * 8 + e;

    for (int idx = tid; idx < 96*64; idx += 256){ int r = idx >> 6, c = idx & 63; sWihz[r][c] = Wih[r*80 + c]; }
    for (int idx = tid; idx < 96*16; idx += 256){ int r = idx >> 4, k = idx & 15; sWiha[r][k] = Wih[r*80 + 64 + k]; }
    for (int idx = tid; idx < 3*8*128; idx += 256){
        int s = idx >> 10, rem = idx & 1023, kq = rem >> 7, r = rem & 127;
        int ii = r >> 2, d = r & 3;
        sWhhQ[s][kq][r] = Whh[(s*32 + ii)*32 + 4*kq + d];
    }
    for (int idx = tid; idx < 16*128; idx += 256){ int k2 = idx >> 7, r = idx & 127, jp = r >> 2, d = r & 3;
        sEncP[k2][4*jp + d] = Wenc[(2*jp + (d&1))*42 + (2*k2 + (d>>1))]; }
    for (int idx = tid; idx < 5*128; idx += 256){ int k2 = idx >> 7, r = idx & 127, jp = r >> 2, d = r & 3;
        sEncEP[k2][4*jp + d] = Wenc[(2*jp + (d&1))*42 + 32 + (2*k2 + (d>>1))]; }
    for (int idx = tid; idx < 10*32; idx += 256){ int o = idx >> 5, k = idx & 31; sWdech[o][k] = Wdec[o*96 + k]; }
    for (int idx = tid; idx < 10*64; idx += 256){ int o = idx >> 6, c = idx & 63; sWdecz[o][c] = Wdec[o*96 + 32 + c]; }
    if (tid < 32){
        sBiasD[tid][0] = (double)bih[tid]      + (double)bhh[tid];       // br
        sBiasD[tid][1] = (double)bih[32+tid]   + (double)bhh[32+tid];    // bz
        sBiasD[tid][2] = (double)bhh[64+tid];                            // bnh
        sBiasD[tid][3] = (double)bih[64+tid];                            // bni
    }
    if (tid < 64) sBencF[tid] = benc[tid];
    __syncthreads();

    const float bd  = (i < 10) ? bdec[i] : 0.0f;
    const int   drow = (i < 10) ? i : 9;

    // h state: fp64 in LDS (broadcast within the element's 32 lanes; same wave)
    double hown = (double)H0[(size_t)n * 32 + i];
    sHd[e][i] = hown;

    const size_t HOFF = (size_t)T_STEPS * NB * 10;
    const size_t ZOFF = HOFF + (size_t)T_STEPS * NB * 32;

    unsigned pack = 0;                        // 8x3-bit winner classes of z_t
    double pgr = 0.0, pgz = 0.0, phn = 0.0;   // carried GRU h-part partials (incl. biases)
    float  ar[16] = {};                       // A[t-1], loaded in previous iteration's tail

    #pragma unroll 1
    for (int t = 0; t < T_STEPS; ++t){
        const size_t tn = (size_t)t * NB + n;

        // issue this step's G/X loads first; HBM latency covered by the GRU below
        float2 g2 = *reinterpret_cast<const float2*>(G + tn*64 + 2*i);
        float ex[10];
        {
            const float* xr = X + tn*10;
            #pragma unroll
            for (int c = 0; c < 5; ++c){
                float2 v = *reinterpret_cast<const float2*>(xr + 2*c);
                ex[2*c] = v.x; ex[2*c+1] = v.y;
            }
        }

        if (t > 0){
            // ---- finish GRU for step t: carried h-part + z-gather + a-part ----
            double gr = pgr, gz = pgz, gn = sBiasD[i][3], hn = phn;
            #pragma unroll
            for (int g = 0; g < 8; ++g){
                int col = 8*g + (int)((pack >> (3*g)) & 7u);
                gr += (double)sWihz[i][col];
                gz += (double)sWihz[32+i][col];
                gn += (double)sWihz[64+i][col];
            }
            #pragma unroll
            for (int c = 0; c < 8; ++c){
                float2 w0 = *reinterpret_cast<const float2*>(&sWiha[i][2*c]);
                float2 w1 = *reinterpret_cast<const float2*>(&sWiha[32+i][2*c]);
                float2 w2 = *reinterpret_cast<const float2*>(&sWiha[64+i][2*c]);
                double a0 = (double)ar[2*c], a1 = (double)ar[2*c+1];
                gr = fma((double)w0.x, a0, gr); gr = fma((double)w0.y, a1, gr);
                gz = fma((double)w1.x, a0, gz); gz = fma((double)w1.y, a1, gz);
                gn = fma((double)w2.x, a0, gn); gn = fma((double)w2.y, a1, gn);
            }
            double rr  = frcp(1.0 + fexp(-gr));
            double zg  = frcp(1.0 + fexp(-gz));
            double arg = gn + rr * hn;
            double e2  = fexp(arg + arg);
            double nn  = fma(-2.0, frcp(e2 + 1.0), 1.0);
            hown = (1.0 - zg) * nn + zg * hown;
            sHd[e][i] = hown;            // publish h_t (in-order within the wave)
        }

        // h_all output (fp32)
        out[HOFF + tn*32 + i] = (float)hown;

        // ---- ENC e-part FIRST (consumes ex -> its 10 regs die before the k-loop) ----
        float2 bev = *reinterpret_cast<const float2*>(&sBencF[2*i]);
        double l0 = (double)bev.x, l1 = (double)bev.y;
        #pragma unroll
        for (int k2 = 0; k2 < 5; ++k2){
            float4 w = *reinterpret_cast<const float4*>(&sEncEP[k2][4*i]);
            double e0 = (double)ex[2*k2], e1 = (double)ex[2*k2+1];
            l0 = fma((double)w.x, e0, l0); l1 = fma((double)w.y, e0, l1);
            l0 = fma((double)w.z, e1, l0); l1 = fma((double)w.w, e1, l1);
        }

        // ---- merged k-loop over h_t: ENC h-part + GRU h-partials(t+1) + DEC h-part ----
        double2 b01 = *reinterpret_cast<const double2*>(&sBiasD[i][0]);
        double ngr = b01.x, ngz = b01.y, nhn = sBiasD[i][2];
        float  dacc = bd;
        #pragma unroll
        for (int c = 0; c < 8; ++c){
            double2 ha = *reinterpret_cast<const double2*>(&sHd[e][4*c]);
            double2 hb = *reinterpret_cast<const double2*>(&sHd[e][4*c+2]);
            const double hk0 = ha.x, hk1 = ha.y, hk2 = hb.x, hk3 = hb.y;
            float4 wa = *reinterpret_cast<const float4*>(&sEncP[2*c][4*i]);
            float4 wb = *reinterpret_cast<const float4*>(&sEncP[2*c+1][4*i]);
            l0 = fma((double)wa.x, hk0, l0); l1 = fma((double)wa.y, hk0, l1);
            l0 = fma((double)wa.z, hk1, l0); l1 = fma((double)wa.w, hk1, l1);
            l0 = fma((double)wb.x, hk2, l0); l1 = fma((double)wb.y, hk2, l1);
            l0 = fma((double)wb.z, hk3, l0); l1 = fma((double)wb.w, hk3, l1);
            float4 wh0 = *reinterpret_cast<const float4*>(&sWhhQ[0][c][4*i]);
            float4 wh1 = *reinterpret_cast<const float4*>(&sWhhQ[1][c][4*i]);
            float4 wh2 = *reinterpret_cast<const float4*>(&sWhhQ[2][c][4*i]);
            ngr = fma((double)wh0.x, hk0, ngr);
            ngr = fma((double)wh0.y, hk1, ngr);
            ngr = fma((double)wh0.z, hk2, ngr);
            ngr = fma((double)wh0.w, hk3, ngr);
            ngz = fma((double)wh1.x, hk0, ngz);
            ngz = fma((double)wh1.y, hk1, ngz);
            ngz = fma((double)wh1.z, hk2, ngz);
            ngz = fma((double)wh1.w, hk3, ngz);
            nhn = fma((double)wh2.x, hk0, nhn);
            nhn = fma((double)wh2.y, hk1, nhn);
            nhn = fma((double)wh2.z, hk2, nhn);
            nhn = fma((double)wh2.w, hk3, nhn);
            float4 wd = *reinterpret_cast<const float4*>(&sWdech[drow][4*c]);
            dacc = fmaf(wd.x, (float)hk0, dacc);
            dacc = fmaf(wd.y, (float)hk1, dacc);
            dacc = fmaf(wd.z, (float)hk2, dacc);
            dacc = fmaf(wd.w, (float)hk3, dacc);
        }

        // issue A[t] load in the light tail region (consumed at next iteration's top)
        {
            const float4* arow = reinterpret_cast<const float4*>(A + tn*16);
            #pragma unroll
            for (int c = 0; c < 4; ++c){
                float4 v = arow[c];
                ar[4*c+0]=v.x; ar[4*c+1]=v.y; ar[4*c+2]=v.z; ar[4*c+3]=v.w;
            }
        }

        // ---- gumbel-argmax over each 8-class group (4-lane cluster) ----
        double y0 = l0 + (double)g2.x, y1 = l1 + (double)g2.y;
        double m; int idxv;
        if (y1 > y0){ m = y1; idxv = 2*i + 1; } else { m = y0; idxv = 2*i; }
        #pragma unroll
        for (int d = 1; d <= 2; d <<= 1){
            double mo = __shfl_xor(m, d, 64);
            int    io = __shfl_xor(idxv, d, 64);
            if (mo > m || (mo == m && io < idxv)){ m = mo; idxv = io; }
        }

        // z one-hot output (fp32)
        {
            float2 zv;
            zv.x = (idxv == 2*i    ) ? 1.0f : 0.0f;
            zv.y = (idxv == 2*i + 1) ? 1.0f : 0.0f;
            *reinterpret_cast<float2*>(out + ZOFF + tn*64 + 2*i) = zv;
        }

        // pack all 8 group winners (3-bit class each) into one u32: 3 or-butterflies
        unsigned pk = ((unsigned)idxv & 7u) << (3*(i >> 2));
        #pragma unroll
        for (int d = 4; d <= 16; d <<= 1) pk |= (unsigned)__shfl_xor((int)pk, d, 64);
        pack = pk;

        // ---- DEC z-part + store (lanes 0..9); x_logits[t] uses h_t, z_t ----
        if (i < 10){
            float acc = dacc;
            #pragma unroll
            for (int g = 0; g < 8; ++g){
                int col = 8*g + (int)((pack >> (3*g)) & 7u);
                acc += sWdecz[i][col];
            }
            out[tn*10 + i] = acc;
        }

        pgr = ngr; pgz = ngz; phn = nhn;   // carry h-part partials to step t+1
    }
}

extern "C" void kernel_launch(void* const* d_in, const int* in_sizes, int n_in,
                              void* d_out, int out_size, void* d_ws, size_t ws_size,
                              hipStream_t stream)
{
    // Defensive input binding by unique element count (no-op if dict order holds).
    const float *x   = (const float*)d_in[0];
    const float *a   = (const float*)d_in[1];
    const float *h0  = (const float*)d_in[2];
    const float *g   = (const float*)d_in[3];
    const float *wih = (const float*)d_in[4];
    const float *bih = (const float*)d_in[5];
    const float *whh = (const float*)d_in[6];
    const float *bhh = (const float*)d_in[7];
    const float *wenc= (const float*)d_in[8];
    const float *benc= (const float*)d_in[9];
    const float *wdec= (const float*)d_in[10];
    const float *bdec= (const float*)d_in[11];

    if (n_in == 12) {
        const float *b96a = nullptr, *b96b = nullptr;
        const float *tx=nullptr,*ta=nullptr,*th0=nullptr,*tg=nullptr,*twih=nullptr,
                    *twhh=nullptr,*twenc=nullptr,*tbenc=nullptr,*twdec=nullptr,*tbdec=nullptr;
        for (int k = 0; k < 12; ++k) {
            const float* p = (const float*)d_in[k];
            switch (in_sizes[k]) {
                case 10485760: tx = p;    break;  // x
                case 16777216: ta = p;    break;  // a
                case 131072:   th0 = p;   break;  // h0
                case 67108864: tg = p;    break;  // gumbel
                case 7680:     twih = p;  break;  // W_ih
                case 3072:     twhh = p;  break;  // W_hh
                case 2688:     twenc = p; break;  // W_enc
                case 64:       tbenc = p; break;  // b_enc
                case 960:      twdec = p; break;  // W_dec
                case 10:       tbdec = p; break;  // b_dec
                case 96:       if (!b96a) b96a = p; else b96b = p; break; // b_ih / b_hh (both zero)
                default: break;
            }
        }
        if (tx && ta && th0 && tg && twih && twhh && twenc && tbenc && twdec && tbdec && b96a && b96b) {
            x = tx; a = ta; h0 = th0; g = tg;
            wih = twih; whh = twhh; wenc = twenc; benc = tbenc; wdec = twdec; bdec = tbdec;
            bih = b96a; bhh = b96b;
        }
    }

    rssm_kernel<<<512, 256, 0, stream>>>(
        x, a, h0, g, wih, bih, whh, bhh, wenc, benc, wdec, bdec,
        (float*)d_out);
}

// Round 16
// 943.952 us; speedup vs baseline: 2.7773x; 2.7773x over previous
//
#include <hip/hip_runtime.h>
#include <math.h>

#define T_STEPS 256
#define NB 4096

// ---- fast fp64 helpers (pure VALU, no LDS) ----
__device__ __forceinline__ double frcp(double d){
    double r;
    asm("v_rcp_f64 %0, %1" : "=v"(r) : "v"(d));
    r = r * fma(-d, r, 2.0);          // NR 1
    r = r * fma(-d, r, 2.0);          // NR 2 -> ~0.5 ulp
    return r;
}
__device__ __forceinline__ double fexp(double y){   // e^y, |y| < ~700, rel err ~1e-13
    const double MAGIC   = 6755399441055744.0;      // 2^52 + 2^51
    const double INV_LN2 = 1.4426950408889634074;
    const double LN2_HI  = 6.93147180369123816490e-01;
    const double LN2_LO  = 1.90821492927058770002e-10;
    double zz = fma(y, INV_LN2, MAGIC);
    int    ni = __double2loint(zz);
    double nd = zz - MAGIC;                         // n (exact)
    double r  = fma(nd, -LN2_HI, y);
    r = fma(nd, -LN2_LO, r);                        // r in [-0.347, 0.347]
    double p = 2.7557319223985890653e-7;            // 1/10!
    p = fma(p, r, 2.7557319223985888276e-6);        // 1/9!
    p = fma(p, r, 2.4801587301587301566e-5);
    p = fma(p, r, 1.9841269841269841253e-4);
    p = fma(p, r, 1.3888888888888889419e-3);
    p = fma(p, r, 8.3333333333333332177e-3);
    p = fma(p, r, 4.1666666666666664354e-2);
    p = fma(p, r, 1.6666666666666665741e-1);
    p = fma(p, r, 5.0e-1);
    p = fma(p, r, 1.0);
    p = fma(p, r, 1.0);                             // e^r
    double sc = __longlong_as_double(((long long)(1023 + ni)) << 52);  // 2^n
    return p * sc;
}

__global__ __launch_bounds__(256, 2)
void rssm_kernel(const float* __restrict__ X, const float* __restrict__ A,
                 const float* __restrict__ H0, const float* __restrict__ G,
                 const float* __restrict__ Wih, const float* __restrict__ bih,
                 const float* __restrict__ Whh, const float* __restrict__ bhh,
                 const float* __restrict__ Wenc, const float* __restrict__ benc,
                 const float* __restrict__ Wdec, const float* __restrict__ bdec,
                 float* __restrict__ out)   // d_out is FP32
{
    // Static LDS, 63,488 B total (2 blocks/CU). All weights + biases in LDS.
    __shared__ float  sWihz[96][65];                    // z-part gather (bank r+c, conflict-free)
    __shared__ float  sWiha[96][18];                    // a-part, float2 reads (2-way-free banks)
    __shared__ __align__(16) float sWhhQ[3][8][132];    // W_hh packed: [gate][kquad][4*i+d], b128 reads
    __shared__ __align__(16) float sEncP [16][132];     // enc h-part packed: [k2][4*jp+d]
    __shared__ __align__(16) float sEncEP[5][132];      // enc e-part packed
    __shared__ __align__(16) float sWdech[10][36];      // dec h-part rows, float4 reads
    __shared__ float  sWdecz[10][65];                   // dec z-part gather
    __shared__ __align__(16) double sHd[8][34];         // per-element fp64 h (broadcast b128 reads)
    __shared__ __align__(16) double sBiasD[32][5];      // {br, bz, bnh, bni} per component (padded)
    __shared__ float  sBencF[64];                       // enc biases

    const int tid = threadIdx.x;
    const int i   = tid & 31;          // component lane within element
    const int e   = tid >> 5;          // element slot in block (0..7)
    const int n   = blockIdx.x * 8 + e;

    for (int idx = tid; idx < 96*64; idx += 256){ int r = idx >> 6, c = idx & 63; sWihz[r][c] = Wih[r*80 + c]; }
    for (int idx = tid; idx < 96*16; idx += 256){ int r = idx >> 4, k = idx & 15; sWiha[r][k] = Wih[r*80 + 64 + k]; }
    for (int idx = tid; idx < 3*8*128; idx += 256){
        int s = idx >> 10, rem = idx & 1023, kq = rem >> 7, r = rem & 127;
        int ii = r >> 2, d = r & 3;
        sWhhQ[s][kq][r] = Whh[(s*32 + ii)*32 + 4*kq + d];
    }
    for (int idx = tid; idx < 16*128; idx += 256){ int k2 = idx >> 7, r = idx & 127, jp = r >> 2, d = r & 3;
        sEncP[k2][4*jp + d] = Wenc[(2*jp + (d&1))*42 + (2*k2 + (d>>1))]; }
    for (int idx = tid; idx < 5*128; idx += 256){ int k2 = idx >> 7, r = idx & 127, jp = r >> 2, d = r & 3;
        sEncEP[k2][4*jp + d] = Wenc[(2*jp + (d&1))*42 + 32 + (2*k2 + (d>>1))]; }
    for (int idx = tid; idx < 10*32; idx += 256){ int o = idx >> 5, k = idx & 31; sWdech[o][k] = Wdec[o*96 + k]; }
    for (int idx = tid; idx < 10*64; idx += 256){ int o = idx >> 6, c = idx & 63; sWdecz[o][c] = Wdec[o*96 + 32 + c]; }
    if (tid < 32){
        sBiasD[tid][0] = (double)bih[tid]      + (double)bhh[tid];       // br
        sBiasD[tid][1] = (double)bih[32+tid]   + (double)bhh[32+tid];    // bz
        sBiasD[tid][2] = (double)bhh[64+tid];                            // bnh
        sBiasD[tid][3] = (double)bih[64+tid];                            // bni
    }
    if (tid < 64) sBencF[tid] = benc[tid];
    __syncthreads();

    const float bd  = (i < 10) ? bdec[i] : 0.0f;
    const int   drow = (i < 10) ? i : 9;

    // h state: fp64 in LDS (broadcast within the element's 32 lanes; same wave)
    double hown = (double)H0[(size_t)n * 32 + i];
    sHd[e][i] = hown;

    const size_t HOFF = (size_t)T_STEPS * NB * 10;
    const size_t ZOFF = HOFF + (size_t)T_STEPS * NB * 32;

    unsigned pack = 0;                        // 8x3-bit winner classes of z_t
    double pgr = 0.0, pgz = 0.0, phn = 0.0;   // carried GRU h-part partials (incl. biases)
    float  ar[16] = {};                       // A[t-1], loaded in previous iteration's tail

    #pragma unroll 1
    for (int t = 0; t < T_STEPS; ++t){
        const size_t tn = (size_t)t * NB + n;

        if (t > 0){
            // ---- finish GRU for step t: carried h-part + z-gather + a-part ----
            double gr = pgr, gz = pgz, gn = sBiasD[i][3], hn = phn;
            #pragma unroll
            for (int g = 0; g < 8; ++g){
                int col = 8*g + (int)((pack >> (3*g)) & 7u);
                gr += (double)sWihz[i][col];
                gz += (double)sWihz[32+i][col];
                gn += (double)sWihz[64+i][col];
            }
            #pragma unroll
            for (int c = 0; c < 8; ++c){
                float2 w0 = *reinterpret_cast<const float2*>(&sWiha[i][2*c]);
                float2 w1 = *reinterpret_cast<const float2*>(&sWiha[32+i][2*c]);
                float2 w2 = *reinterpret_cast<const float2*>(&sWiha[64+i][2*c]);
                double a0 = (double)ar[2*c], a1 = (double)ar[2*c+1];
                gr = fma((double)w0.x, a0, gr); gr = fma((double)w0.y, a1, gr);
                gz = fma((double)w1.x, a0, gz); gz = fma((double)w1.y, a1, gz);
                gn = fma((double)w2.x, a0, gn); gn = fma((double)w2.y, a1, gn);
            }
            double rr  = frcp(1.0 + fexp(-gr));
            double zg  = frcp(1.0 + fexp(-gz));
            double arg = gn + rr * hn;
            double e2  = fexp(arg + arg);
            double nn  = fma(-2.0, frcp(e2 + 1.0), 1.0);
            hown = (1.0 - zg) * nn + zg * hown;
            sHd[e][i] = hown;            // publish h_t (in-order within the wave)
        }

        // issue this step's G/X loads here: covered by the ~1100-cy k-loop below;
        // ar[] is dead now (consumed above), so these 12 regs replace its liveness
        float2 g2 = *reinterpret_cast<const float2*>(G + tn*64 + 2*i);
        float ex[10];
        {
            const float* xr = X + tn*10;
            #pragma unroll
            for (int c = 0; c < 5; ++c){
                float2 v = *reinterpret_cast<const float2*>(xr + 2*c);
                ex[2*c] = v.x; ex[2*c+1] = v.y;
            }
        }

        // h_all output (fp32)
        out[HOFF + tn*32 + i] = (float)hown;

        // ---- merged k-loop over h_t: ENC(t) logits + GRU h-partials(t+1) + DEC h-part(t) ----
        // unroll 2 (not full): caps the scheduler's in-flight load window so the
        // 11 accumulators + 2x32 load regs fit under the 128-VGPR / 8-wave budget.
        double2 b01 = *reinterpret_cast<const double2*>(&sBiasD[i][0]);
        double ngr = b01.x, ngz = b01.y, nhn = sBiasD[i][2];
        float2 bev = *reinterpret_cast<const float2*>(&sBencF[2*i]);
        double l0 = (double)bev.x, l1 = (double)bev.y;
        float  dacc = bd;
        #pragma unroll 2
        for (int c = 0; c < 8; ++c){
            double2 ha = *reinterpret_cast<const double2*>(&sHd[e][4*c]);
            double2 hb = *reinterpret_cast<const double2*>(&sHd[e][4*c+2]);
            const double hk0 = ha.x, hk1 = ha.y, hk2 = hb.x, hk3 = hb.y;
            float4 wa = *reinterpret_cast<const float4*>(&sEncP[2*c][4*i]);
            float4 wb = *reinterpret_cast<const float4*>(&sEncP[2*c+1][4*i]);
            l0 = fma((double)wa.x, hk0, l0); l1 = fma((double)wa.y, hk0, l1);
            l0 = fma((double)wa.z, hk1, l0); l1 = fma((double)wa.w, hk1, l1);
            l0 = fma((double)wb.x, hk2, l0); l1 = fma((double)wb.y, hk2, l1);
            l0 = fma((double)wb.z, hk3, l0); l1 = fma((double)wb.w, hk3, l1);
            float4 wh0 = *reinterpret_cast<const float4*>(&sWhhQ[0][c][4*i]);
            float4 wh1 = *reinterpret_cast<const float4*>(&sWhhQ[1][c][4*i]);
            float4 wh2 = *reinterpret_cast<const float4*>(&sWhhQ[2][c][4*i]);
            ngr = fma((double)wh0.x, hk0, ngr);
            ngr = fma((double)wh0.y, hk1, ngr);
            ngr = fma((double)wh0.z, hk2, ngr);
            ngr = fma((double)wh0.w, hk3, ngr);
            ngz = fma((double)wh1.x, hk0, ngz);
            ngz = fma((double)wh1.y, hk1, ngz);
            ngz = fma((double)wh1.z, hk2, ngz);
            ngz = fma((double)wh1.w, hk3, ngz);
            nhn = fma((double)wh2.x, hk0, nhn);
            nhn = fma((double)wh2.y, hk1, nhn);
            nhn = fma((double)wh2.z, hk2, nhn);
            nhn = fma((double)wh2.w, hk3, nhn);
            float4 wd = *reinterpret_cast<const float4*>(&sWdech[drow][4*c]);
            dacc = fmaf(wd.x, (float)hk0, dacc);
            dacc = fmaf(wd.y, (float)hk1, dacc);
            dacc = fmaf(wd.z, (float)hk2, dacc);
            dacc = fmaf(wd.w, (float)hk3, dacc);
        }
        #pragma unroll
        for (int k2 = 0; k2 < 5; ++k2){   // ENC e-part
            float4 w = *reinterpret_cast<const float4*>(&sEncEP[k2][4*i]);
            double e0 = (double)ex[2*k2], e1 = (double)ex[2*k2+1];
            l0 = fma((double)w.x, e0, l0); l1 = fma((double)w.y, e0, l1);
            l0 = fma((double)w.z, e1, l0); l1 = fma((double)w.w, e1, l1);
        }

        // issue A[t] load in the light tail region (consumed at next iteration's top;
        // covered by argmax + dec + stores + next z/a-gather)
        {
            const float4* arow = reinterpret_cast<const float4*>(A + tn*16);
            #pragma unroll
            for (int c = 0; c < 4; ++c){
                float4 v = arow[c];
                ar[4*c+0]=v.x; ar[4*c+1]=v.y; ar[4*c+2]=v.z; ar[4*c+3]=v.w;
            }
        }

        // ---- gumbel-argmax over each 8-class group (4-lane cluster) ----
        double y0 = l0 + (double)g2.x, y1 = l1 + (double)g2.y;
        double m; int idxv;
        if (y1 > y0){ m = y1; idxv = 2*i + 1; } else { m = y0; idxv = 2*i; }
        #pragma unroll
        for (int d = 1; d <= 2; d <<= 1){
            double mo = __shfl_xor(m, d, 64);
            int    io = __shfl_xor(idxv, d, 64);
            if (mo > m || (mo == m && io < idxv)){ m = mo; idxv = io; }
        }

        // z one-hot output (fp32)
        {
            float2 zv;
            zv.x = (idxv == 2*i    ) ? 1.0f : 0.0f;
            zv.y = (idxv == 2*i + 1) ? 1.0f : 0.0f;
            *reinterpret_cast<float2*>(out + ZOFF + tn*64 + 2*i) = zv;
        }

        // pack all 8 group winners (3-bit class each) into one u32: 3 or-butterflies
        unsigned pk = ((unsigned)idxv & 7u) << (3*(i >> 2));
        #pragma unroll
        for (int d = 4; d <= 16; d <<= 1) pk |= (unsigned)__shfl_xor((int)pk, d, 64);
        pack = pk;

        // ---- DEC z-part + store (lanes 0..9); x_logits[t] uses h_t, z_t ----
        if (i < 10){
            float acc = dacc;
            #pragma unroll
            for (int g = 0; g < 8; ++g){
                int col = 8*g + (int)((pack >> (3*g)) & 7u);
                acc += sWdecz[i][col];
            }
            out[tn*10 + i] = acc;
        }

        pgr = ngr; pgz = ngz; phn = nhn;   // carry h-part partials to step t+1
    }
}

extern "C" void kernel_launch(void* const* d_in, const int* in_sizes, int n_in,
                              void* d_out, int out_size, void* d_ws, size_t ws_size,
                              hipStream_t stream)
{
    // Defensive input binding by unique element count (no-op if dict order holds).
    const float *x   = (const float*)d_in[0];
    const float *a   = (const float*)d_in[1];
    const float *h0  = (const float*)d_in[2];
    const float *g   = (const float*)d_in[3];
    const float *wih = (const float*)d_in[4];
    const float *bih = (const float*)d_in[5];
    const float *whh = (const float*)d_in[6];
    const float *bhh = (const float*)d_in[7];
    const float *wenc= (const float*)d_in[8];
    const float *benc= (const float*)d_in[9];
    const float *wdec= (const float*)d_in[10];
    const float *bdec= (const float*)d_in[11];

    if (n_in == 12) {
        const float *b96a = nullptr, *b96b = nullptr;
        const float *tx=nullptr,*ta=nullptr,*th0=nullptr,*tg=nullptr,*twih=nullptr,
                    *twhh=nullptr,*twenc=nullptr,*tbenc=nullptr,*twdec=nullptr,*tbdec=nullptr;
        for (int k = 0; k < 12; ++k) {
            const float* p = (const float*)d_in[k];
            switch (in_sizes[k]) {
                case 10485760: tx = p;    break;  // x
                case 16777216: ta = p;    break;  // a
                case 131072:   th0 = p;   break;  // h0
                case 67108864: tg = p;    break;  // gumbel
                case 7680:     twih = p;  break;  // W_ih
                case 3072:     twhh = p;  break;  // W_hh
                case 2688:     twenc = p; break;  // W_enc
                case 64:       tbenc = p; break;  // b_enc
                case 960:      twdec = p; break;  // W_dec
                case 10:       tbdec = p; break;  // b_dec
                case 96:       if (!b96a) b96a = p; else b96b = p; break; // b_ih / b_hh (both zero)
                default: break;
            }
        }
        if (tx && ta && th0 && tg && twih && twhh && twenc && tbenc && twdec && tbdec && b96a && b96b) {
            x = tx; a = ta; h0 = th0; g = tg;
            wih = twih; whh = twhh; wenc = twenc; benc = tbenc; wdec = twdec; bdec = tbdec;
            bih = b96a; bhh = b96b;
        }
    }

    rssm_kernel<<<512, 256, 0, stream>>>(
        x, a, h0, g, wih, bih, whh, bhh, wenc, benc, wdec, bdec,
        (float*)d_out);
}

// Round 17
// 928.012 us; speedup vs baseline: 2.8250x; 1.0172x over previous
//
#include <hip/hip_runtime.h>
#include <math.h>

#define T_STEPS 256
#define NB 4096

// ---- fast fp64 helpers (pure VALU, no LDS) ----
__device__ __forceinline__ double frcp(double d){
    double r;
    asm("v_rcp_f64 %0, %1" : "=v"(r) : "v"(d));
    r = r * fma(-d, r, 2.0);          // NR 1
    r = r * fma(-d, r, 2.0);          // NR 2 -> ~0.5 ulp
    return r;
}
__device__ __forceinline__ double fexp(double y){   // e^y, |y| < ~700, rel err ~1e-13
    const double MAGIC   = 6755399441055744.0;      // 2^52 + 2^51
    const double INV_LN2 = 1.4426950408889634074;
    const double LN2_HI  = 6.93147180369123816490e-01;
    const double LN2_LO  = 1.90821492927058770002e-10;
    double zz = fma(y, INV_LN2, MAGIC);
    int    ni = __double2loint(zz);
    double nd = zz - MAGIC;                         // n (exact)
    double r  = fma(nd, -LN2_HI, y);
    r = fma(nd, -LN2_LO, r);                        // r in [-0.347, 0.347]
    double p = 2.7557319223985890653e-7;            // 1/10!
    p = fma(p, r, 2.7557319223985888276e-6);        // 1/9!
    p = fma(p, r, 2.4801587301587301566e-5);
    p = fma(p, r, 1.9841269841269841253e-4);
    p = fma(p, r, 1.3888888888888889419e-3);
    p = fma(p, r, 8.3333333333333332177e-3);
    p = fma(p, r, 4.1666666666666664354e-2);
    p = fma(p, r, 1.6666666666666665741e-1);
    p = fma(p, r, 5.0e-1);
    p = fma(p, r, 1.0);
    p = fma(p, r, 1.0);                             // e^r
    double sc = __longlong_as_double(((long long)(1023 + ni)) << 52);  // 2^n
    return p * sc;
}

__global__ __launch_bounds__(256, 2)
void rssm_kernel(const float* __restrict__ X, const float* __restrict__ A,
                 const float* __restrict__ H0, const float* __restrict__ G,
                 const float* __restrict__ Wih, const float* __restrict__ bih,
                 const float* __restrict__ Whh, const float* __restrict__ bhh,
                 const float* __restrict__ Wenc, const float* __restrict__ benc,
                 const float* __restrict__ Wdec, const float* __restrict__ bdec,
                 float* __restrict__ out)   // d_out is FP32
{
    // Static LDS ~61.4 KB (2 blocks/CU). Weights in LDS; biases in registers.
    __shared__ float  sWihz[96][65];                    // z-part gather (bank r+c, conflict-free)
    __shared__ __align__(16) float sWihaQ[3][4][132];   // a-part packed: [gate][kquad][4*i+d], b128 reads
    __shared__ __align__(16) float sWhhQ[3][8][132];    // W_hh packed: [gate][kquad][4*i+d], b128 reads
    __shared__ __align__(16) float sEncP [16][132];     // enc h-part packed: [k2][4*jp+d]
    __shared__ __align__(16) float sEncEP[5][132];      // enc e-part packed
    __shared__ __align__(16) float sWdech[10][36];      // dec h-part rows, float4 reads
    __shared__ float  sWdecz[10][65];                   // dec z-part gather
    __shared__ __align__(16) double sHd[8][34];         // per-element fp64 h (broadcast b128 reads)

    const int tid = threadIdx.x;
    const int i   = tid & 31;          // component lane within element
    const int e   = tid >> 5;          // element slot in block (0..7)
    const int n   = blockIdx.x * 8 + e;

    for (int idx = tid; idx < 96*64; idx += 256){ int r = idx >> 6, c = idx & 63; sWihz[r][c] = Wih[r*80 + c]; }
    for (int idx = tid; idx < 3*4*128; idx += 256){
        int s = idx >> 9, rem = idx & 511, kq = rem >> 7, r = rem & 127;
        int ii = r >> 2, d = r & 3;
        sWihaQ[s][kq][r] = Wih[(s*32 + ii)*80 + 64 + 4*kq + d];
    }
    for (int idx = tid; idx < 3*8*128; idx += 256){
        int s = idx >> 10, rem = idx & 1023, kq = rem >> 7, r = rem & 127;
        int ii = r >> 2, d = r & 3;
        sWhhQ[s][kq][r] = Whh[(s*32 + ii)*32 + 4*kq + d];
    }
    for (int idx = tid; idx < 16*128; idx += 256){ int k2 = idx >> 7, r = idx & 127, jp = r >> 2, d = r & 3;
        sEncP[k2][4*jp + d] = Wenc[(2*jp + (d&1))*42 + (2*k2 + (d>>1))]; }
    for (int idx = tid; idx < 5*128; idx += 256){ int k2 = idx >> 7, r = idx & 127, jp = r >> 2, d = r & 3;
        sEncEP[k2][4*jp + d] = Wenc[(2*jp + (d&1))*42 + 32 + (2*k2 + (d>>1))]; }
    for (int idx = tid; idx < 10*32; idx += 256){ int o = idx >> 5, k = idx & 31; sWdech[o][k] = Wdec[o*96 + k]; }
    for (int idx = tid; idx < 10*64; idx += 256){ int o = idx >> 6, c = idx & 63; sWdecz[o][c] = Wdec[o*96 + 32 + c]; }
    __syncthreads();

    // biases in registers (r,z gates merge b_ih+b_hh; n gate split: b_hh[n] in r*h_n)
    const double br  = (double)bih[i]      + (double)bhh[i];
    const double bz  = (double)bih[32+i]   + (double)bhh[32+i];
    const double bnh = (double)bhh[64+i];
    const double bni = (double)bih[64+i];
    const double be0 = (double)benc[2*i], be1 = (double)benc[2*i+1];
    const float  bd  = (i < 10) ? bdec[i] : 0.0f;
    const int    drow = (i < 10) ? i : 9;

    // h state: fp64 in LDS (broadcast within the element's 32 lanes; same wave)
    double hown = (double)H0[(size_t)n * 32 + i];
    sHd[e][i] = hown;

    const size_t HOFF = (size_t)T_STEPS * NB * 10;
    const size_t ZOFF = HOFF + (size_t)T_STEPS * NB * 32;

    unsigned pack = 0;                        // 8x3-bit winner classes of z_t
    double pgr = 0.0, pgz = 0.0, phn = 0.0;   // carried GRU h-part partials (incl. biases)
    float  ar[16] = {};                       // A[t-1], loaded in previous iteration's tail

    #pragma unroll 1
    for (int t = 0; t < T_STEPS; ++t){
        const size_t tn = (size_t)t * NB + n;

        if (t > 0){
            // ---- finish GRU for step t: carried h-part + z-gather + a-part ----
            double gr = pgr, gz = pgz, gn = bni, hn = phn;
            #pragma unroll
            for (int g = 0; g < 8; ++g){
                int col = 8*g + (int)((pack >> (3*g)) & 7u);
                gr += (double)sWihz[i][col];
                gz += (double)sWihz[32+i][col];
                gn += (double)sWihz[64+i][col];
            }
            #pragma unroll
            for (int q = 0; q < 4; ++q){   // a-part: b128 quads, ascending cols (same fma order)
                float4 w0 = *reinterpret_cast<const float4*>(&sWihaQ[0][q][4*i]);
                float4 w1 = *reinterpret_cast<const float4*>(&sWihaQ[1][q][4*i]);
                float4 w2 = *reinterpret_cast<const float4*>(&sWihaQ[2][q][4*i]);
                double a0 = (double)ar[4*q], a1 = (double)ar[4*q+1];
                double a2 = (double)ar[4*q+2], a3 = (double)ar[4*q+3];
                gr = fma((double)w0.x, a0, gr); gr = fma((double)w0.y, a1, gr);
                gr = fma((double)w0.z, a2, gr); gr = fma((double)w0.w, a3, gr);
                gz = fma((double)w1.x, a0, gz); gz = fma((double)w1.y, a1, gz);
                gz = fma((double)w1.z, a2, gz); gz = fma((double)w1.w, a3, gz);
                gn = fma((double)w2.x, a0, gn); gn = fma((double)w2.y, a1, gn);
                gn = fma((double)w2.z, a2, gn); gn = fma((double)w2.w, a3, gn);
            }
            double rr  = frcp(1.0 + fexp(-gr));
            double zg  = frcp(1.0 + fexp(-gz));
            double arg = gn + rr * hn;
            double e2  = fexp(arg + arg);
            double nn  = fma(-2.0, frcp(e2 + 1.0), 1.0);
            hown = (1.0 - zg) * nn + zg * hown;
            sHd[e][i] = hown;            // publish h_t (in-order within the wave)
        }

        // issue this step's G/X loads here: covered by the ~1100-cy k-loop below
        float2 g2 = *reinterpret_cast<const float2*>(G + tn*64 + 2*i);
        float ex[10];
        {
            const float* xr = X + tn*10;
            #pragma unroll
            for (int c = 0; c < 5; ++c){
                float2 v = *reinterpret_cast<const float2*>(xr + 2*c);
                ex[2*c] = v.x; ex[2*c+1] = v.y;
            }
        }

        // h_all output (fp32)
        out[HOFF + tn*32 + i] = (float)hown;

        // ---- merged k-loop over h_t: ENC(t) logits + GRU h-partials(t+1) + DEC h-part(t) ----
        // unroll 2 (not full): caps in-flight loads so pressure stays under 128 VGPR.
        double ngr = br, ngz = bz, nhn = bnh;
        double l0 = be0, l1 = be1;
        float  dacc = bd;
        #pragma unroll 2
        for (int c = 0; c < 8; ++c){
            double2 ha = *reinterpret_cast<const double2*>(&sHd[e][4*c]);
            double2 hb = *reinterpret_cast<const double2*>(&sHd[e][4*c+2]);
            const double hk0 = ha.x, hk1 = ha.y, hk2 = hb.x, hk3 = hb.y;
            float4 wa = *reinterpret_cast<const float4*>(&sEncP[2*c][4*i]);
            float4 wb = *reinterpret_cast<const float4*>(&sEncP[2*c+1][4*i]);
            l0 = fma((double)wa.x, hk0, l0); l1 = fma((double)wa.y, hk0, l1);
            l0 = fma((double)wa.z, hk1, l0); l1 = fma((double)wa.w, hk1, l1);
            l0 = fma((double)wb.x, hk2, l0); l1 = fma((double)wb.y, hk2, l1);
            l0 = fma((double)wb.z, hk3, l0); l1 = fma((double)wb.w, hk3, l1);
            float4 wh0 = *reinterpret_cast<const float4*>(&sWhhQ[0][c][4*i]);
            float4 wh1 = *reinterpret_cast<const float4*>(&sWhhQ[1][c][4*i]);
            float4 wh2 = *reinterpret_cast<const float4*>(&sWhhQ[2][c][4*i]);
            ngr = fma((double)wh0.x, hk0, ngr);
            ngr = fma((double)wh0.y, hk1, ngr);
            ngr = fma((double)wh0.z, hk2, ngr);
            ngr = fma((double)wh0.w, hk3, ngr);
            ngz = fma((double)wh1.x, hk0, ngz);
            ngz = fma((double)wh1.y, hk1, ngz);
            ngz = fma((double)wh1.z, hk2, ngz);
            ngz = fma((double)wh1.w, hk3, ngz);
            nhn = fma((double)wh2.x, hk0, nhn);
            nhn = fma((double)wh2.y, hk1, nhn);
            nhn = fma((double)wh2.z, hk2, nhn);
            nhn = fma((double)wh2.w, hk3, nhn);
            float4 wd = *reinterpret_cast<const float4*>(&sWdech[drow][4*c]);
            dacc = fmaf(wd.x, (float)hk0, dacc);
            dacc = fmaf(wd.y, (float)hk1, dacc);
            dacc = fmaf(wd.z, (float)hk2, dacc);
            dacc = fmaf(wd.w, (float)hk3, dacc);
        }
        #pragma unroll
        for (int k2 = 0; k2 < 5; ++k2){   // ENC e-part
            float4 w = *reinterpret_cast<const float4*>(&sEncEP[k2][4*i]);
            double e0 = (double)ex[2*k2], e1 = (double)ex[2*k2+1];
            l0 = fma((double)w.x, e0, l0); l1 = fma((double)w.y, e0, l1);
            l0 = fma((double)w.z, e1, l0); l1 = fma((double)w.w, e1, l1);
        }

        // issue A[t] load in the light tail region (consumed at next iteration's top)
        {
            const float4* arow = reinterpret_cast<const float4*>(A + tn*16);
            #pragma unroll
            for (int c = 0; c < 4; ++c){
                float4 v = arow[c];
                ar[4*c+0]=v.x; ar[4*c+1]=v.y; ar[4*c+2]=v.z; ar[4*c+3]=v.w;
            }
        }

        // ---- gumbel-argmax over each 8-class group (4-lane cluster) ----
        double y0 = l0 + (double)g2.x, y1 = l1 + (double)g2.y;
        double m; int idxv;
        if (y1 > y0){ m = y1; idxv = 2*i + 1; } else { m = y0; idxv = 2*i; }
        #pragma unroll
        for (int d = 1; d <= 2; d <<= 1){
            double mo = __shfl_xor(m, d, 64);
            int    io = __shfl_xor(idxv, d, 64);
            if (mo > m || (mo == m && io < idxv)){ m = mo; idxv = io; }
        }

        // z one-hot output (fp32)
        {
            float2 zv;
            zv.x = (idxv == 2*i    ) ? 1.0f : 0.0f;
            zv.y = (idxv == 2*i + 1) ? 1.0f : 0.0f;
            *reinterpret_cast<float2*>(out + ZOFF + tn*64 + 2*i) = zv;
        }

        // pack all 8 group winners (3-bit class each) into one u32: 3 or-butterflies
        unsigned pk = ((unsigned)idxv & 7u) << (3*(i >> 2));
        #pragma unroll
        for (int d = 4; d <= 16; d <<= 1) pk |= (unsigned)__shfl_xor((int)pk, d, 64);
        pack = pk;

        // ---- DEC z-part + store (lanes 0..9); x_logits[t] uses h_t, z_t ----
        if (i < 10){
            float acc = dacc;
            #pragma unroll
            for (int g = 0; g < 8; ++g){
                int col = 8*g + (int)((pack >> (3*g)) & 7u);
                acc += sWdecz[i][col];
            }
            out[tn*10 + i] = acc;
        }

        pgr = ngr; pgz = ngz; phn = nhn;   // carry h-part partials to step t+1
    }
}

extern "C" void kernel_launch(void* const* d_in, const int* in_sizes, int n_in,
                              void* d_out, int out_size, void* d_ws, size_t ws_size,
                              hipStream_t stream)
{
    // Defensive input binding by unique element count (no-op if dict order holds).
    const float *x   = (const float*)d_in[0];
    const float *a   = (const float*)d_in[1];
    const float *h0  = (const float*)d_in[2];
    const float *g   = (const float*)d_in[3];
    const float *wih = (const float*)d_in[4];
    const float *bih = (const float*)d_in[5];
    const float *whh = (const float*)d_in[6];
    const float *bhh = (const float*)d_in[7];
    const float *wenc= (const float*)d_in[8];
    const float *benc= (const float*)d_in[9];
    const float *wdec= (const float*)d_in[10];
    const float *bdec= (const float*)d_in[11];

    if (n_in == 12) {
        const float *b96a = nullptr, *b96b = nullptr;
        const float *tx=nullptr,*ta=nullptr,*th0=nullptr,*tg=nullptr,*twih=nullptr,
                    *twhh=nullptr,*twenc=nullptr,*tbenc=nullptr,*twdec=nullptr,*tbdec=nullptr;
        for (int k = 0; k < 12; ++k) {
            const float* p = (const float*)d_in[k];
            switch (in_sizes[k]) {
                case 10485760: tx = p;    break;  // x
                case 16777216: ta = p;    break;  // a
                case 131072:   th0 = p;   break;  // h0
                case 67108864: tg = p;    break;  // gumbel
                case 7680:     twih = p;  break;  // W_ih
                case 3072:     twhh = p;  break;  // W_hh
                case 2688:     twenc = p; break;  // W_enc
                case 64:       tbenc = p; break;  // b_enc
                case 960:      twdec = p; break;  // W_dec
                case 10:       tbdec = p; break;  // b_dec
                case 96:       if (!b96a) b96a = p; else b96b = p; break; // b_ih / b_hh (both zero)
                default: break;
            }
        }
        if (tx && ta && th0 && tg && twih && twhh && twenc && tbenc && twdec && tbdec && b96a && b96b) {
            x = tx; a = ta; h0 = th0; g = tg;
            wih = twih; whh = twhh; wenc = twenc; benc = tbenc; wdec = twdec; bdec = tbdec;
            bih = b96a; bhh = b96b;
        }
    }

    rssm_kernel<<<512, 256, 0, stream>>>(
        x, a, h0, g, wih, bih, whh, bhh, wenc, benc, wdec, bdec,
        (float*)d_out);
}